// Round 20
// baseline (414.441 us; speedup 1.0000x reference)
//
#include <hip/hip_runtime.h>
#include <hip/hip_bf16.h>

// GRU-like fused cell: out = (1-z)*tanh(i_n + r*h_n) + z*e
// B=8, H=512, N=8192. bf16 MFMA 16x16x32, fp32 acc, fused epilogue.
//
// R19 -> R20: R19's 32x32 shape regressed (bank audit wrong: 1.26e7 conflicts)
// and targeted the wrong pipe anyway -- R17 is LDS-PORT-bound (120KB/WG-step
// ~= 80% of slot; A = 72KB of it). R20 removes A from LDS: wimg re-laid
// fragment-linear, A-frags loaded global->VGPR (L2-hot, 1KB coalesced/wave).
// LDS = B only (48KB/WG-step), 3x16KB triple-buffer, ONE barrier/step.
// vm-count is order-robust: [compute w/ compiler-waited A-loads][sched_barrier]
// [4 B-DMAs][sched_barrier][vmcnt(4)] -- newest 4 ops are exactly the DMAs.

#define HH 512
#define NBATCH 8
#define NN 8192
#define BN 128
#define NSTEPS 16
#define THREADS 256
#define BBUF 16384                      // B-only buffer
#define LDS_DMA (3 * BBUF)              // 49152/WG -> 2 WGs/CU easily
// fallback (R16) geometry:
#define A_BYTES (192 * 64 * 2)          // 24576
#define FB_BUF (A_BYTES + BBUF)         // 40960
#define LDS_FB (2 * FB_BUF)             // 81920

#define WIMG_BYTES (NBATCH * NSTEPS * 12288 * 2)          // 3,145,728 (both layouts)
#define XIMG_BYTES ((size_t)NBATCH * NSTEPS * 64 * 16384) // 134,217,728
#define WS_NEED (WIMG_BYTES + XIMG_BYTES)

typedef __attribute__((ext_vector_type(8))) short short8;
typedef __attribute__((ext_vector_type(4))) float f32x4;

__device__ __forceinline__ unsigned cvt_pk_bf16(float a, float b) {
  unsigned r;
  asm("v_cvt_pk_bf16_f32 %0, %1, %2" : "=v"(r) : "v"(a), "v"(b));
  return r;
}

__device__ __forceinline__ void gload_lds16(const void* g, void* l) {
  __builtin_amdgcn_global_load_lds(
      (__attribute__((address_space(1))) void*)(g),
      (__attribute__((address_space(3))) void*)(l), 16, 0, 0);
}

#define MFMA16(a_, b_, c_) __builtin_amdgcn_mfma_f32_16x16x32_bf16((a_), (b_), (c_), 0, 0, 0)
#define LD8(p) (*(const short8*)(p))

#define BARRIER_FENCED() do {                               \
    __builtin_amdgcn_sched_barrier(0);                      \
    __builtin_amdgcn_s_barrier();                           \
    __builtin_amdgcn_sched_barrier(0);                      \
  } while (0)

// ---------------- weight pre-pack, FRAGMENT-LINEAR (for gru_main_dma) --------
// slot t = (((((ht*16+s)*2+wm)*2+kb2)*3+gate)*2+mi)*64+lane ; 16B per slot.
// Lane l of frag holds A[row = gate*512 + ht*64+wm*32+mi*16+(l&15)]
//                      [k = s*64 + kb2*32 + (l>>4)*8 .. +8) as 8 bf16.
__global__ void prepack_w_frag(const float* __restrict__ W_ih,
                               const float* __restrict__ W_hh,
                               __hip_bfloat16* __restrict__ ws) {
  int t = blockIdx.x * 256 + threadIdx.x;   // 0..196607
  int lane = t & 63; int u = t >> 6;
  int mi = u & 1;   u >>= 1;
  int gate = u % 3; u /= 3;
  int kb2 = u & 1;  u >>= 1;
  int wm = u & 1;   u >>= 1;
  int s = u & 15;   u >>= 4;
  int ht = u;
  int grow = gate * HH + ht * 64 + wm * 32 + mi * 16 + (lane & 15);
  int kg = s * 64 + kb2 * 32 + ((lane >> 4) << 3);
  const float* src = (kg < 512) ? (W_ih + (size_t)grow * 512 + kg)
                                : (W_hh + (size_t)grow * 512 + (kg - 512));
  unsigned w[4];
#pragma unroll
  for (int j = 0; j < 4; ++j) w[j] = cvt_pk_bf16(src[2 * j], src[2 * j + 1]);
  *(uint4*)((char*)ws + (size_t)t * 16) = make_uint4(w[0], w[1], w[2], w[3]);
}

// ---------------- weight pre-pack, OLD LDS-image layout (for fallback) -------
__global__ void prepack_w_lds(const float* __restrict__ W_ih, const float* __restrict__ W_hh,
                              __hip_bfloat16* __restrict__ ws) {
  int t = blockIdx.x * 256 + threadIdx.x;
  int blk = t / 12288;
  int e = t % 12288;
  int ra = e >> 6;
  int kk = (e & 63) ^ ((ra & 7) << 3);
  int gate = ra >> 6;
  int h = (blk >> 4) * 64 + (ra & 63);
  int row = gate * HH + h;
  int kg = (blk & 15) * 64 + kk;
  float v = (kg < 512) ? W_ih[row * 512 + kg] : W_hh[row * 512 + (kg - 512)];
  ws[t] = __float2bfloat16(v);
}

// ---------------- X pre-pack (unchanged, verified R17-R19) ----------------
__global__ void prepack_x(const float* __restrict__ e_wv, const float* __restrict__ m_wv,
                          char* __restrict__ ximg) {
  __shared__ __align__(16) char tile[16384];
  const int tid = threadIdx.x;
  const int idx = blockIdx.x;               // 0..8191
  const int b  = idx >> 10;
  const int s  = (idx >> 6) & 15;
  const int nt = idx & 63;
  const float* src = (s < 8 ? m_wv : e_wv)
                   + (size_t)b * HH * NN + (size_t)(64 * (s & 7)) * NN + nt * 128;
#pragma unroll
  for (int it = 0; it < 8; ++it) {
    int g = it * 256 + tid;
    int k = g >> 5;
    int n4 = (g & 31) << 2;
    f32x4 v = *(const f32x4*)(src + (size_t)k * NN + n4);
#pragma unroll
    for (int j = 0; j < 4; ++j) {
      int n = n4 + j;
      int byteoff = n * 128 + ((2 * k) ^ (((n >> 1) & 7) << 4));
      *(__hip_bfloat16*)(tile + byteoff) = __float2bfloat16(v[j]);
    }
  }
  __syncthreads();
  char* dst = ximg + (size_t)idx * 16384;
#pragma unroll
  for (int it = 0; it < 4; ++it) {
    int p = it * 4096 + tid * 16;
    *(uint4*)(dst + p) = *(const uint4*)(tile + p);
  }
}

// ---------------- main: A global->reg (L2), B-only LDS, 3-buf, 1 barrier/step
__global__ __launch_bounds__(THREADS, 2)
void gru_main_dma(const float* __restrict__ e_wv,
                  const __hip_bfloat16* __restrict__ wimg,
                  const char* __restrict__ ximg, float* __restrict__ out) {
  extern __shared__ char smem[];
  const int tid  = threadIdx.x;
  const int lane = tid & 63;
  const int wave = tid >> 6;       // 0..3
  const int wm = wave >> 1;        // 0..1 : 32-row half of 64-h tile
  const int wn = wave & 1;         // 0..1 : 64-col half of 128-n tile

  // XCD swizzle (bijective: 4096 % 8 == 0), ht fastest.
  const int wg  = blockIdx.x;
  const int swz = (wg & 7) * 512 + (wg >> 3);
  const int ht  = swz & 7;
  const int nt  = (swz >> 3) & 63;
  const int b   = swz >> 9;

  const size_t batch_off = (size_t)b * HH * NN;
  // A fragment base: (ht,s) stride 24576; wm slice 12288; +lane*16.
  const char* wA  = (const char*)wimg + ((size_t)(ht * 16) * 2 + wm) * 12288 + lane * 16;
  const char* xib = ximg + ((size_t)(b * 16) * 64 + nt) * 16384 + tid * 16;

  f32x4 acc_r[2][4]  = {};
  f32x4 acc_z[2][4]  = {};
  f32x4 acc_in[2][4] = {};
  f32x4 acc_hn[2][4] = {};

  // B read offsets (R12/R16/R17-verified swizzle, 0 conflicts), B-only buffer.
  int boff[2];
#pragma unroll
  for (int kb2 = 0; kb2 < 2; ++kb2) {
    const int K = kb2 * 64 + ((lane >> 4) << 4);
    boff[kb2] = (wn * 64 + (lane & 15)) * 128 + (K ^ (((lane >> 1) & 7) << 4));
  }

  auto stage = [&](int t, char* buf) {   // 4 B DMAs only
    const char* gB = xib + (size_t)t * (64 * 16384);
    char* lB = buf + tid * 16;
#pragma unroll
    for (int i = 0; i < 4; ++i)
      gload_lds16(gB + i * 4096, lB + i * 4096);
  };
  auto compute_step = [&](const char* cb, int s, bool firstHalf) {
    const char* aS = wA + (size_t)s * 24576;
#pragma unroll
    for (int kb2 = 0; kb2 < 2; ++kb2) {
      const char* aK = aS + kb2 * 6144;
      short8 bfr[4];
#pragma unroll
      for (int ni = 0; ni < 4; ++ni)
        bfr[ni] = LD8(cb + boff[kb2] + ni * 2048);
      {  // gate r
        short8 a0 = LD8(aK);
        short8 a1 = LD8(aK + 1024);
#pragma unroll
        for (int ni = 0; ni < 4; ++ni) {
          acc_r[0][ni] = MFMA16(a0, bfr[ni], acc_r[0][ni]);
          acc_r[1][ni] = MFMA16(a1, bfr[ni], acc_r[1][ni]);
        }
      }
      {  // gate z
        short8 a0 = LD8(aK + 2048);
        short8 a1 = LD8(aK + 3072);
#pragma unroll
        for (int ni = 0; ni < 4; ++ni) {
          acc_z[0][ni] = MFMA16(a0, bfr[ni], acc_z[0][ni]);
          acc_z[1][ni] = MFMA16(a1, bfr[ni], acc_z[1][ni]);
        }
      }
      {  // gate n -> acc_in (m-phase) / acc_hn (e-phase)
        short8 a0 = LD8(aK + 4096);
        short8 a1 = LD8(aK + 5120);
        if (firstHalf) {
#pragma unroll
          for (int ni = 0; ni < 4; ++ni) {
            acc_in[0][ni] = MFMA16(a0, bfr[ni], acc_in[0][ni]);
            acc_in[1][ni] = MFMA16(a1, bfr[ni], acc_in[1][ni]);
          }
        } else {
#pragma unroll
          for (int ni = 0; ni < 4; ++ni) {
            acc_hn[0][ni] = MFMA16(a0, bfr[ni], acc_hn[0][ni]);
            acc_hn[1][ni] = MFMA16(a1, bfr[ni], acc_hn[1][ni]);
          }
        }
      }
    }
  };

  // prologue: B(0)->buf0, B(1)->buf1; wait B(0) (4 newest = B(1)); barrier.
  stage(0, smem);
  stage(1, smem + BBUF);
  asm volatile("s_waitcnt vmcnt(4)" ::: "memory");
  BARRIER_FENCED();

#pragma unroll 1
  for (int t = 0; t < NSTEPS; ++t) {
    char* cb = smem + (t % 3) * BBUF;
    const bool firstHalf = (t < 8);

    compute_step(cb, t, firstHalf);   // A-loads compiler-waited (L2-hot)

    __builtin_amdgcn_sched_barrier(0);
    if (t + 2 < NSTEPS) {
      stage(t + 2, smem + ((t + 2) % 3) * BBUF);   // 4 newest vm ops
      __builtin_amdgcn_sched_barrier(0);
      // retire everything except the 4 DMAs just issued -> B(t+1) landed,
      // B(t+2) stays in flight. Count is order-robust (sched_barrier fenced).
      asm volatile("s_waitcnt vmcnt(4) lgkmcnt(0)" ::: "memory");
    } else {
      asm volatile("s_waitcnt vmcnt(0) lgkmcnt(0)" ::: "memory");
    }
    if (t < NSTEPS - 1) BARRIER_FENCED();
  }

  // epilogue: gates + blend (unchanged, verified R1-R19)
  const size_t obase = batch_off + (size_t)(ht * 64 + wm * 32) * NN + nt * BN + wn * 64;
  const float* ep = e_wv + obase;
  float* op = out + obase;
  const int rsub = (lane >> 4) << 2;
  const int csub = lane & 15;
#pragma unroll
  for (int mi = 0; mi < 2; ++mi)
#pragma unroll
    for (int ni = 0; ni < 4; ++ni) {
#pragma unroll
      for (int r = 0; r < 4; ++r) {
        size_t idx = (size_t)(mi * 16 + rsub + r) * NN + ni * 16 + csub;
        float pr  = acc_r[mi][ni][r];
        float pz  = acc_z[mi][ni][r];
        float vin = acc_in[mi][ni][r];
        float vhn = acc_hn[mi][ni][r];
        float rr  = 1.f / (1.f + __expf(-pr));
        float zz  = 1.f / (1.f + __expf(-pz));
        float ex  = __expf(2.f * (vin + rr * vhn));
        float nn2 = 1.f - 2.f / (ex + 1.f);      // tanh, inf-safe
        float ev  = ep[idx];
        op[idx] = (1.f - zz) * nn2 + zz * ev;
      }
    }
}

// ---------------- fallback: R16 verbatim (old wimg layout; small-ws path) ----
__global__ __launch_bounds__(THREADS, 2)
void gru_main_fb(const float* __restrict__ e_wv, const float* __restrict__ m_wv,
                 const __hip_bfloat16* __restrict__ wimg, float* __restrict__ out) {
  extern __shared__ char smem[];
  const int tid  = threadIdx.x;
  const int lane = tid & 63;
  const int wave = tid >> 6;
  const int wm = wave >> 1;
  const int wn = wave & 1;
  const int wg  = blockIdx.x;
  const int swz = (wg & 7) * 512 + (wg >> 3);
  const int ht  = swz & 7;
  const int nt  = (swz >> 3) & 63;
  const int b   = swz >> 9;
  const size_t batch_off = (size_t)b * HH * NN;
  const float* xm = m_wv + batch_off + (size_t)(16 * wave) * NN + nt * BN + 2 * lane;
  const float* xe = e_wv + batch_off + (size_t)(16 * wave) * NN + nt * BN + 2 * lane;
  const char*  wA = (const char*)wimg + (size_t)ht * NSTEPS * A_BYTES + tid * 16;
  f32x4 acc_r[2][4]  = {};
  f32x4 acc_z[2][4]  = {};
  f32x4 acc_in[2][4] = {};
  f32x4 acc_hn[2][4] = {};
  float2 xR[16];
  int aoff[2], boff[2];
#pragma unroll
  for (int kb2 = 0; kb2 < 2; ++kb2) {
    const int K = kb2 * 64 + ((lane >> 4) << 4);
    aoff[kb2] = (wm * 32 + (lane & 15)) * 128 + (K ^ ((lane & 7) << 4));
    boff[kb2] = A_BYTES + (wn * 64 + (lane & 15)) * 128 + (K ^ (((lane >> 1) & 7) << 4));
  }
  auto issue_A = [&](int s, char* nb) {
    const char* gA = wA + (size_t)s * A_BYTES;
    char* lA = nb + tid * 16;
#pragma unroll
    for (int i = 0; i < 6; ++i) gload_lds16(gA + i * 4096, lA + i * 4096);
  };
  auto x_load = [&](const float* xs) {
#pragma unroll
    for (int i = 0; i < 16; ++i) xR[i] = *(const float2*)(xs + (size_t)i * NN);
  };
  auto write_X = [&](char* nb) {
    char* Bb = nb + A_BYTES + (2 * lane) * 128;
    const int sx = (lane & 7) << 4;
#pragma unroll
    for (int o = 0; o < 2; ++o) {
      uint4 w0, w1;
      w0.x = cvt_pk_bf16(xR[8 * o + 0].x, xR[8 * o + 1].x);
      w0.y = cvt_pk_bf16(xR[8 * o + 2].x, xR[8 * o + 3].x);
      w0.z = cvt_pk_bf16(xR[8 * o + 4].x, xR[8 * o + 5].x);
      w0.w = cvt_pk_bf16(xR[8 * o + 6].x, xR[8 * o + 7].x);
      w1.x = cvt_pk_bf16(xR[8 * o + 0].y, xR[8 * o + 1].y);
      w1.y = cvt_pk_bf16(xR[8 * o + 2].y, xR[8 * o + 3].y);
      w1.z = cvt_pk_bf16(xR[8 * o + 4].y, xR[8 * o + 5].y);
      w1.w = cvt_pk_bf16(xR[8 * o + 6].y, xR[8 * o + 7].y);
      const int kb = (32 * wave + 16 * o) ^ sx;
      *(uint4*)(Bb + kb)       = w0;
      *(uint4*)(Bb + 128 + kb) = w1;
    }
  };
  auto compute_kb2 = [&](const char* cb, int kb2, bool firstHalf) {
    short8 bfr[4];
#pragma unroll
    for (int ni = 0; ni < 4; ++ni) bfr[ni] = *(const short8*)(cb + boff[kb2] + ni * 2048);
    {
      short8 a0 = *(const short8*)(cb + aoff[kb2]);
      short8 a1 = *(const short8*)(cb + aoff[kb2] + 2048);
#pragma unroll
      for (int ni = 0; ni < 4; ++ni) {
        acc_r[0][ni] = MFMA16(a0, bfr[ni], acc_r[0][ni]);
        acc_r[1][ni] = MFMA16(a1, bfr[ni], acc_r[1][ni]);
      }
    }
    {
      short8 a0 = *(const short8*)(cb + aoff[kb2] + 8192);
      short8 a1 = *(const short8*)(cb + aoff[kb2] + 8192 + 2048);
#pragma unroll
      for (int ni = 0; ni < 4; ++ni) {
        acc_z[0][ni] = MFMA16(a0, bfr[ni], acc_z[0][ni]);
        acc_z[1][ni] = MFMA16(a1, bfr[ni], acc_z[1][ni]);
      }
    }
    {
      short8 a0 = *(const short8*)(cb + aoff[kb2] + 16384);
      short8 a1 = *(const short8*)(cb + aoff[kb2] + 16384 + 2048);
      if (firstHalf) {
#pragma unroll
        for (int ni = 0; ni < 4; ++ni) {
          acc_in[0][ni] = MFMA16(a0, bfr[ni], acc_in[0][ni]);
          acc_in[1][ni] = MFMA16(a1, bfr[ni], acc_in[1][ni]);
        }
      } else {
#pragma unroll
        for (int ni = 0; ni < 4; ++ni) {
          acc_hn[0][ni] = MFMA16(a0, bfr[ni], acc_hn[0][ni]);
          acc_hn[1][ni] = MFMA16(a1, bfr[ni], acc_hn[1][ni]);
        }
      }
    }
  };
  issue_A(0, smem);
  x_load(xm);
  write_X(smem);
  __syncthreads();
#pragma unroll 1
  for (int s = 0; s < NSTEPS; ++s) {
    char* cb = smem + ((s & 1) ? FB_BUF : 0);
    char* nb = smem + ((s & 1) ? 0 : FB_BUF);
    const bool pre = (s < NSTEPS - 1);
    const bool firstHalf = (s < 8);
    if (pre) {
      const int t = s + 1;
      x_load((t < 8 ? xm : xe) + (size_t)(t & 7) * (64 * NN));
      issue_A(t, nb);
    }
    compute_kb2(cb, 0, firstHalf);
    compute_kb2(cb, 1, firstHalf);
    if (pre) write_X(nb);
    __syncthreads();
  }
  const size_t obase = batch_off + (size_t)(ht * 64 + wm * 32) * NN + nt * BN + wn * 64;
  const float* ep = e_wv + obase;
  float* op = out + obase;
  const int rsub = (lane >> 4) << 2;
  const int csub = lane & 15;
#pragma unroll
  for (int mi = 0; mi < 2; ++mi)
#pragma unroll
    for (int ni = 0; ni < 4; ++ni) {
#pragma unroll
      for (int r = 0; r < 4; ++r) {
        size_t idx = (size_t)(mi * 16 + rsub + r) * NN + ni * 16 + csub;
        float pr  = acc_r[mi][ni][r];
        float pz  = acc_z[mi][ni][r];
        float vin = acc_in[mi][ni][r];
        float vhn = acc_hn[mi][ni][r];
        float rr  = 1.f / (1.f + __expf(-pr));
        float zz  = 1.f / (1.f + __expf(-pz));
        float ex  = __expf(2.f * (vin + rr * vhn));
        float nn2 = 1.f - 2.f / (ex + 1.f);
        float ev  = ep[idx];
        op[idx] = (1.f - zz) * nn2 + zz * ev;
      }
    }
}

extern "C" void kernel_launch(void* const* d_in, const int* in_sizes, int n_in,
                              void* d_out, int out_size, void* d_ws, size_t ws_size,
                              hipStream_t stream) {
  const float* e_wv = (const float*)d_in[0];
  const float* m_wv = (const float*)d_in[1];
  const float* W_ih = (const float*)d_in[2];
  const float* W_hh = (const float*)d_in[3];
  float* out = (float*)d_out;
  __hip_bfloat16* wimg = (__hip_bfloat16*)d_ws;
  char* ximg = (char*)d_ws + WIMG_BYTES;

  (void)hipFuncSetAttribute((const void*)gru_main_dma,
                            hipFuncAttributeMaxDynamicSharedMemorySize, LDS_DMA);
  (void)hipFuncSetAttribute((const void*)gru_main_fb,
                            hipFuncAttributeMaxDynamicSharedMemorySize, LDS_FB);

  if (ws_size >= WS_NEED) {
    prepack_w_frag<<<196608 / 256, 256, 0, stream>>>(W_ih, W_hh, wimg);
    prepack_x<<<NBATCH * NSTEPS * 64, 256, 0, stream>>>(e_wv, m_wv, ximg);
    gru_main_dma<<<NBATCH * 8 * 64, THREADS, LDS_DMA, stream>>>(e_wv, wimg, ximg, out);
  } else {
    prepack_w_lds<<<(NBATCH * NSTEPS * 12288) / 256, 256, 0, stream>>>(W_ih, W_hh, wimg);
    gru_main_fb<<<NBATCH * 8 * 64, THREADS, LDS_FB, stream>>>(e_wv, m_wv, wimg, out);
  }
}

// Round 21
// 309.805 us; speedup vs baseline: 1.3377x; 1.3377x over previous
//
#include <hip/hip_runtime.h>
#include <hip/hip_bf16.h>

// GRU-like fused cell: out = (1-z)*tanh(i_n + r*h_n) + z*e
// B=8, H=512, N=8192. bf16 MFMA 16x16x32, fp32 acc, fused epilogue.
//
// R20 -> R21: RESTORE R17 (verified optimum: main 258.6us, bench 308).
// R20's A-from-global regressed (A reads 96KB/slot from L2 @ ~56B/cyc/CU
// ~= 1700cyc > the 1875cyc LDS port it tried to relieve, + exposed latency).
// R17 structure: all-DMA staging (type-pure vm domain), counted vmcnt(10)
// depth-2 pipeline, pre-swizzled weight image + X image (prepack_x),
// conflict-free LDS layouts, XCD swizzle, 2 WGs/CU. Measured at ~78% of the
// LDS-port structural floor; R18 (phase-split), R19 (32x32), R20 (A-global)
// all regressed -- this is the final kernel.

#define HH 512
#define NBATCH 8
#define NN 8192
#define BN 128
#define BK 64
#define NSTEPS 16
#define THREADS 256
#define A_BYTES (192 * BK * 2)          // 24576
#define B_BYTES (BN * 128)              // 16384
#define BUF_BYTES (A_BYTES + B_BYTES)   // 40960
#define LDS_TOTAL (2 * BUF_BYTES)       // 81920 -> 2 WGs/CU

#define WIMG_BYTES (NBATCH * NSTEPS * 12288 * 2)          // 3,145,728
#define XIMG_BYTES ((size_t)NBATCH * NSTEPS * 64 * 16384) // 134,217,728
#define WS_NEED (WIMG_BYTES + XIMG_BYTES)

typedef __attribute__((ext_vector_type(8))) short short8;
typedef __attribute__((ext_vector_type(4))) float f32x4;

__device__ __forceinline__ unsigned cvt_pk_bf16(float a, float b) {
  unsigned r;
  asm("v_cvt_pk_bf16_f32 %0, %1, %2" : "=v"(r) : "v"(a), "v"(b));
  return r;
}

__device__ __forceinline__ void gload_lds16(const void* g, void* l) {
  __builtin_amdgcn_global_load_lds(
      (__attribute__((address_space(1))) void*)(g),
      (__attribute__((address_space(3))) void*)(l), 16, 0, 0);
}

#define MFMA16(a_, b_, c_) __builtin_amdgcn_mfma_f32_16x16x32_bf16((a_), (b_), (c_), 0, 0, 0)

#define BARRIER_FENCED() do {                               \
    __builtin_amdgcn_sched_barrier(0);                      \
    __builtin_amdgcn_s_barrier();                           \
    __builtin_amdgcn_sched_barrier(0);                      \
  } while (0)

// ---------------- weight pre-pack (verified R1-R18) ----------------
__global__ void prepack_w(const float* __restrict__ W_ih, const float* __restrict__ W_hh,
                          __hip_bfloat16* __restrict__ ws) {
  int t = blockIdx.x * 256 + threadIdx.x;
  int blk = t / 12288;                              // ht*16 + s
  int e = t % 12288;
  int ra = e >> 6;                                  // 0..191
  int kk = (e & 63) ^ ((ra & 7) << 3);              // inverse of read-side XOR swizzle
  int gate = ra >> 6;
  int h = (blk >> 4) * 64 + (ra & 63);
  int row = gate * HH + h;
  int kg = (blk & 15) * 64 + kk;
  float v = (kg < 512) ? W_ih[row * 512 + kg] : W_hh[row * 512 + (kg - 512)];
  ws[t] = __float2bfloat16(v);
}

// ---------------- X pre-pack: f32 [k][n] -> bf16 image, byte-identical to the
// LDS B-tile layout: stored_byte(n,k) = n*128 + ((2k) ^ ((n>>1&7)<<4))
__global__ void prepack_x(const float* __restrict__ e_wv, const float* __restrict__ m_wv,
                          char* __restrict__ ximg) {
  __shared__ __align__(16) char tile[16384];
  const int tid = threadIdx.x;
  const int idx = blockIdx.x;               // 0..8191
  const int b  = idx >> 10;
  const int s  = (idx >> 6) & 15;
  const int nt = idx & 63;
  const float* src = (s < 8 ? m_wv : e_wv)
                   + (size_t)b * HH * NN + (size_t)(64 * (s & 7)) * NN + nt * 128;
#pragma unroll
  for (int it = 0; it < 8; ++it) {
    int g = it * 256 + tid;
    int k = g >> 5;
    int n4 = (g & 31) << 2;
    f32x4 v = *(const f32x4*)(src + (size_t)k * NN + n4);
#pragma unroll
    for (int j = 0; j < 4; ++j) {
      int n = n4 + j;
      int byteoff = n * 128 + ((2 * k) ^ (((n >> 1) & 7) << 4));
      *(__hip_bfloat16*)(tile + byteoff) = __float2bfloat16(v[j]);
    }
  }
  __syncthreads();
  char* dst = ximg + (size_t)idx * 16384;
#pragma unroll
  for (int it = 0; it < 4; ++it) {
    int p = it * 4096 + tid * 16;
    *(uint4*)(dst + p) = *(const uint4*)(tile + p);
  }
}

// ---------------- main fused kernel, all-DMA staging (R17, verified) ----------
__global__ __launch_bounds__(THREADS, 2)
void gru_main_dma(const float* __restrict__ e_wv,
                  const __hip_bfloat16* __restrict__ wimg,
                  const char* __restrict__ ximg, float* __restrict__ out) {
  extern __shared__ char smem[];
  const int tid  = threadIdx.x;
  const int lane = tid & 63;
  const int wave = tid >> 6;       // 0..3
  const int wm = wave >> 1;        // 0..1 : 32-row half of 64-h tile
  const int wn = wave & 1;         // 0..1 : 64-col half of 128-n tile

  // XCD swizzle (bijective: 4096 % 8 == 0), ht fastest.
  const int wg  = blockIdx.x;
  const int swz = (wg & 7) * 512 + (wg >> 3);
  const int ht  = swz & 7;
  const int nt  = (swz >> 3) & 63;
  const int b   = swz >> 9;

  const size_t batch_off = (size_t)b * HH * NN;
  const char* wA  = (const char*)wimg + (size_t)ht * NSTEPS * A_BYTES + tid * 16;
  const char* xib = ximg + ((size_t)(b * 16) * 64 + nt) * 16384 + tid * 16;

  f32x4 acc_r[2][4]  = {};
  f32x4 acc_z[2][4]  = {};
  f32x4 acc_in[2][4] = {};
  f32x4 acc_hn[2][4] = {};

  // Read offsets (R12/R16/R17-verified, 0 conflicts).
  int aoff[2], boff[2];
#pragma unroll
  for (int kb2 = 0; kb2 < 2; ++kb2) {
    const int K = kb2 * 64 + ((lane >> 4) << 4);
    aoff[kb2] = (wm * 32 + (lane & 15)) * 128 + (K ^ ((lane & 7) << 4));
    boff[kb2] = A_BYTES + (wn * 64 + (lane & 15)) * 128
              + (K ^ (((lane >> 1) & 7) << 4));
  }

  auto stage = [&](int t, char* buf) {   // 10 gload_lds, type-pure vm domain
    const char* gA = wA + (size_t)t * A_BYTES;
    char* lA = buf + tid * 16;
#pragma unroll
    for (int i = 0; i < 6; ++i)
      gload_lds16(gA + i * 4096, lA + i * 4096);
    const char* gB = xib + (size_t)t * (64 * 16384);
    char* lB = buf + A_BYTES + tid * 16;
#pragma unroll
    for (int i = 0; i < 4; ++i)
      gload_lds16(gB + i * 4096, lB + i * 4096);
  };
  auto compute_kb2 = [&](const char* cb, int kb2, bool firstHalf) {
    short8 bfr[4];
#pragma unroll
    for (int ni = 0; ni < 4; ++ni)
      bfr[ni] = *(const short8*)(cb + boff[kb2] + ni * 2048);
    {  // gate r
      short8 a0 = *(const short8*)(cb + aoff[kb2]);
      short8 a1 = *(const short8*)(cb + aoff[kb2] + 2048);
#pragma unroll
      for (int ni = 0; ni < 4; ++ni) {
        acc_r[0][ni] = MFMA16(a0, bfr[ni], acc_r[0][ni]);
        acc_r[1][ni] = MFMA16(a1, bfr[ni], acc_r[1][ni]);
      }
    }
    {  // gate z
      short8 a0 = *(const short8*)(cb + aoff[kb2] + 8192);
      short8 a1 = *(const short8*)(cb + aoff[kb2] + 8192 + 2048);
#pragma unroll
      for (int ni = 0; ni < 4; ++ni) {
        acc_z[0][ni] = MFMA16(a0, bfr[ni], acc_z[0][ni]);
        acc_z[1][ni] = MFMA16(a1, bfr[ni], acc_z[1][ni]);
      }
    }
    {  // gate n -> acc_in (m-phase) / acc_hn (e-phase)
      short8 a0 = *(const short8*)(cb + aoff[kb2] + 16384);
      short8 a1 = *(const short8*)(cb + aoff[kb2] + 16384 + 2048);
      if (firstHalf) {
#pragma unroll
        for (int ni = 0; ni < 4; ++ni) {
          acc_in[0][ni] = MFMA16(a0, bfr[ni], acc_in[0][ni]);
          acc_in[1][ni] = MFMA16(a1, bfr[ni], acc_in[1][ni]);
        }
      } else {
#pragma unroll
        for (int ni = 0; ni < 4; ++ni) {
          acc_hn[0][ni] = MFMA16(a0, bfr[ni], acc_hn[0][ni]);
          acc_hn[1][ni] = MFMA16(a1, bfr[ni], acc_hn[1][ni]);
        }
      }
    }
  };

  // prologue: stage t0 -> buf0, t1 -> buf1; wait own t0 batch; barrier.
  stage(0, smem);
  stage(1, smem + BUF_BYTES);
  asm volatile("s_waitcnt vmcnt(10)" ::: "memory");   // t0 landed; t1 in flight
  BARRIER_FENCED();

#pragma unroll 1
  for (int t = 0; t < NSTEPS; ++t) {
    char* cb = smem + ((t & 1) ? BUF_BYTES : 0);
    const bool firstHalf = (t < 8);

    compute_kb2(cb, 0, firstHalf);
    compute_kb2(cb, 1, firstHalf);

    // barrier A: all waves done READING cb (ds_reads retired via lgkm)
    asm volatile("s_waitcnt lgkmcnt(0)" ::: "memory");
    BARRIER_FENCED();

    if (t + 2 < NSTEPS) stage(t + 2, cb);   // refill the just-freed buffer

    if (t + 1 < NSTEPS) {
      // barrier B: everyone's t+1 batch landed; t+2 stays in flight.
      if (t + 2 < NSTEPS)
        asm volatile("s_waitcnt vmcnt(10)" ::: "memory");
      else
        asm volatile("s_waitcnt vmcnt(0)" ::: "memory");
      BARRIER_FENCED();
    }
  }

  // epilogue: gates + blend (verified R1-R17)
  const size_t obase = batch_off + (size_t)(ht * 64 + wm * 32) * NN + nt * BN + wn * 64;
  const float* ep = e_wv + obase;
  float* op = out + obase;
  const int rsub = (lane >> 4) << 2;
  const int csub = lane & 15;
#pragma unroll
  for (int mi = 0; mi < 2; ++mi)
#pragma unroll
    for (int ni = 0; ni < 4; ++ni) {
#pragma unroll
      for (int r = 0; r < 4; ++r) {
        size_t idx = (size_t)(mi * 16 + rsub + r) * NN + ni * 16 + csub;
        float pr  = acc_r[mi][ni][r];
        float pz  = acc_z[mi][ni][r];
        float vin = acc_in[mi][ni][r];
        float vhn = acc_hn[mi][ni][r];
        float rr  = 1.f / (1.f + __expf(-pr));
        float zz  = 1.f / (1.f + __expf(-pz));
        float ex  = __expf(2.f * (vin + rr * vhn));
        float nn2 = 1.f - 2.f / (ex + 1.f);      // tanh, inf-safe
        float ev  = ep[idx];
        op[idx] = (1.f - zz) * nn2 + zz * ev;
      }
    }
}

// ---------------- fallback: R16 verbatim (used when ws is too small) ----------------
__global__ __launch_bounds__(THREADS, 2)
void gru_main_fb(const float* __restrict__ e_wv, const float* __restrict__ m_wv,
                 const __hip_bfloat16* __restrict__ wimg, float* __restrict__ out) {
  extern __shared__ char smem[];
  const int tid  = threadIdx.x;
  const int lane = tid & 63;
  const int wave = tid >> 6;
  const int wm = wave >> 1;
  const int wn = wave & 1;
  const int wg  = blockIdx.x;
  const int swz = (wg & 7) * 512 + (wg >> 3);
  const int ht  = swz & 7;
  const int nt  = (swz >> 3) & 63;
  const int b   = swz >> 9;
  const size_t batch_off = (size_t)b * HH * NN;
  const float* xm = m_wv + batch_off + (size_t)(16 * wave) * NN + nt * BN + 2 * lane;
  const float* xe = e_wv + batch_off + (size_t)(16 * wave) * NN + nt * BN + 2 * lane;
  const char*  wA = (const char*)wimg + (size_t)ht * NSTEPS * A_BYTES + tid * 16;
  f32x4 acc_r[2][4]  = {};
  f32x4 acc_z[2][4]  = {};
  f32x4 acc_in[2][4] = {};
  f32x4 acc_hn[2][4] = {};
  float2 xR[16];
  int aoff[2], boff[2];
#pragma unroll
  for (int kb2 = 0; kb2 < 2; ++kb2) {
    const int K = kb2 * 64 + ((lane >> 4) << 4);
    aoff[kb2] = (wm * 32 + (lane & 15)) * 128 + (K ^ ((lane & 7) << 4));
    boff[kb2] = A_BYTES + (wn * 64 + (lane & 15)) * 128 + (K ^ (((lane >> 1) & 7) << 4));
  }
  auto issue_A = [&](int s, char* nb) {
    const char* gA = wA + (size_t)s * A_BYTES;
    char* lA = nb + tid * 16;
#pragma unroll
    for (int i = 0; i < 6; ++i) gload_lds16(gA + i * 4096, lA + i * 4096);
  };
  auto x_load = [&](const float* xs) {
#pragma unroll
    for (int i = 0; i < 16; ++i) xR[i] = *(const float2*)(xs + (size_t)i * NN);
  };
  auto write_X = [&](char* nb) {
    char* Bb = nb + A_BYTES + (2 * lane) * 128;
    const int sx = (lane & 7) << 4;
#pragma unroll
    for (int o = 0; o < 2; ++o) {
      uint4 w0, w1;
      w0.x = cvt_pk_bf16(xR[8 * o + 0].x, xR[8 * o + 1].x);
      w0.y = cvt_pk_bf16(xR[8 * o + 2].x, xR[8 * o + 3].x);
      w0.z = cvt_pk_bf16(xR[8 * o + 4].x, xR[8 * o + 5].x);
      w0.w = cvt_pk_bf16(xR[8 * o + 6].x, xR[8 * o + 7].x);
      w1.x = cvt_pk_bf16(xR[8 * o + 0].y, xR[8 * o + 1].y);
      w1.y = cvt_pk_bf16(xR[8 * o + 2].y, xR[8 * o + 3].y);
      w1.z = cvt_pk_bf16(xR[8 * o + 4].y, xR[8 * o + 5].y);
      w1.w = cvt_pk_bf16(xR[8 * o + 6].y, xR[8 * o + 7].y);
      const int kb = (32 * wave + 16 * o) ^ sx;
      *(uint4*)(Bb + kb)       = w0;
      *(uint4*)(Bb + 128 + kb) = w1;
    }
  };
  auto compute_kb2 = [&](const char* cb, int kb2, bool firstHalf) {
    short8 bfr[4];
#pragma unroll
    for (int ni = 0; ni < 4; ++ni) bfr[ni] = *(const short8*)(cb + boff[kb2] + ni * 2048);
    {
      short8 a0 = *(const short8*)(cb + aoff[kb2]);
      short8 a1 = *(const short8*)(cb + aoff[kb2] + 2048);
#pragma unroll
      for (int ni = 0; ni < 4; ++ni) {
        acc_r[0][ni] = MFMA16(a0, bfr[ni], acc_r[0][ni]);
        acc_r[1][ni] = MFMA16(a1, bfr[ni], acc_r[1][ni]);
      }
    }
    {
      short8 a0 = *(const short8*)(cb + aoff[kb2] + 8192);
      short8 a1 = *(const short8*)(cb + aoff[kb2] + 8192 + 2048);
#pragma unroll
      for (int ni = 0; ni < 4; ++ni) {
        acc_z[0][ni] = MFMA16(a0, bfr[ni], acc_z[0][ni]);
        acc_z[1][ni] = MFMA16(a1, bfr[ni], acc_z[1][ni]);
      }
    }
    {
      short8 a0 = *(const short8*)(cb + aoff[kb2] + 16384);
      short8 a1 = *(const short8*)(cb + aoff[kb2] + 16384 + 2048);
      if (firstHalf) {
#pragma unroll
        for (int ni = 0; ni < 4; ++ni) {
          acc_in[0][ni] = MFMA16(a0, bfr[ni], acc_in[0][ni]);
          acc_in[1][ni] = MFMA16(a1, bfr[ni], acc_in[1][ni]);
        }
      } else {
#pragma unroll
        for (int ni = 0; ni < 4; ++ni) {
          acc_hn[0][ni] = MFMA16(a0, bfr[ni], acc_hn[0][ni]);
          acc_hn[1][ni] = MFMA16(a1, bfr[ni], acc_hn[1][ni]);
        }
      }
    }
  };
  issue_A(0, smem);
  x_load(xm);
  write_X(smem);
  __syncthreads();
#pragma unroll 1
  for (int s = 0; s < NSTEPS; ++s) {
    char* cb = smem + ((s & 1) ? BUF_BYTES : 0);
    char* nb = smem + ((s & 1) ? 0 : BUF_BYTES);
    const bool pre = (s < NSTEPS - 1);
    const bool firstHalf = (s < 8);
    if (pre) {
      const int t = s + 1;
      x_load((t < 8 ? xm : xe) + (size_t)(t & 7) * (64 * NN));
      issue_A(t, nb);
    }
    compute_kb2(cb, 0, firstHalf);
    compute_kb2(cb, 1, firstHalf);
    if (pre) write_X(nb);
    __syncthreads();
  }
  const size_t obase = batch_off + (size_t)(ht * 64 + wm * 32) * NN + nt * BN + wn * 64;
  const float* ep = e_wv + obase;
  float* op = out + obase;
  const int rsub = (lane >> 4) << 2;
  const int csub = lane & 15;
#pragma unroll
  for (int mi = 0; mi < 2; ++mi)
#pragma unroll
    for (int ni = 0; ni < 4; ++ni) {
#pragma unroll
      for (int r = 0; r < 4; ++r) {
        size_t idx = (size_t)(mi * 16 + rsub + r) * NN + ni * 16 + csub;
        float pr  = acc_r[mi][ni][r];
        float pz  = acc_z[mi][ni][r];
        float vin = acc_in[mi][ni][r];
        float vhn = acc_hn[mi][ni][r];
        float rr  = 1.f / (1.f + __expf(-pr));
        float zz  = 1.f / (1.f + __expf(-pz));
        float ex  = __expf(2.f * (vin + rr * vhn));
        float nn2 = 1.f - 2.f / (ex + 1.f);
        float ev  = ep[idx];
        op[idx] = (1.f - zz) * nn2 + zz * ev;
      }
    }
}

extern "C" void kernel_launch(void* const* d_in, const int* in_sizes, int n_in,
                              void* d_out, int out_size, void* d_ws, size_t ws_size,
                              hipStream_t stream) {
  const float* e_wv = (const float*)d_in[0];
  const float* m_wv = (const float*)d_in[1];
  const float* W_ih = (const float*)d_in[2];
  const float* W_hh = (const float*)d_in[3];
  float* out = (float*)d_out;
  __hip_bfloat16* wimg = (__hip_bfloat16*)d_ws;
  char* ximg = (char*)d_ws + WIMG_BYTES;

  (void)hipFuncSetAttribute((const void*)gru_main_dma,
                            hipFuncAttributeMaxDynamicSharedMemorySize, LDS_TOTAL);
  (void)hipFuncSetAttribute((const void*)gru_main_fb,
                            hipFuncAttributeMaxDynamicSharedMemorySize, LDS_TOTAL);

  prepack_w<<<(NBATCH * NSTEPS * 12288) / 256, 256, 0, stream>>>(W_ih, W_hh, wimg);

  if (ws_size >= WS_NEED) {
    prepack_x<<<NBATCH * NSTEPS * 64, 256, 0, stream>>>(e_wv, m_wv, ximg);
    gru_main_dma<<<NBATCH * 8 * 64, THREADS, LDS_TOTAL, stream>>>(e_wv, wimg, ximg, out);
  } else {
    gru_main_fb<<<NBATCH * 8 * 64, THREADS, LDS_TOTAL, stream>>>(e_wv, m_wv, wimg, out);
  }
}